// Round 5
// baseline (246.501 us; speedup 1.0000x reference)
//
#include <hip/hip_runtime.h>
#include <hip/hip_fp16.h>

// Fixed problem instance: B=16384, L=336, H=168, T=504.
// Two-pass: (1) LDS-tile transpose [b][t]fp32 -> [t/8][b]fp16 in workspace,
// (2) sequential KF scan with fully lane-contiguous 16B loads.
// Fallback to the R4 wave-specialized kernel if ws_size < 77 MB.
namespace {
constexpr int kB = 16384;
constexpr int kL = 336;
constexpr int kH = 168;
constexpr int kT = 504;
constexpr int kC8 = 63;            // 8-step chunks per row (63*8 = 504)
constexpr int kFiltC8 = 42;        // chunks 0..41 filter (42*8 == 336), 42..62 forecast
constexpr size_t kStreamU4 = (size_t)kC8 * kB;          // uint4 elems per stream
constexpr size_t kWsNeed = (4 * (size_t)kC8 + 42) * (size_t)kB * 16;  // 77,070,336 B
}

// ---------------------------------------------------------------------------
// Pass 1: transpose + fp32->fp16. grid(256 rowgroups, 2 tiles, 5 streams).
// Tile: 64 rows x 256 floats (t-offsets 0 and 248; chunk 31 written twice).
// ---------------------------------------------------------------------------
__global__ __launch_bounds__(256)
void xpose_kernel(const float* __restrict__ g_obs,
                  const float* __restrict__ g_air,
                  const float* __restrict__ g_wind,
                  const float* __restrict__ g_par,
                  const float* __restrict__ g_dt,
                  uint4* __restrict__ ws4)
{
    extern __shared__ float tile[];  // 64 * 260 floats
    const int tid = threadIdx.x, wid = tid >> 6, lane = tid & 63;
    const int r0 = blockIdx.x * 64;
    const int tb = blockIdx.y;       // 0,1
    const int s  = blockIdx.z;       // 0=air,1=wind,2=par,3=dt,4=obs
    const float* src = s == 0 ? g_air : s == 1 ? g_wind : s == 2 ? g_par
                     : s == 3 ? g_dt  : g_obs;
    uint4* dst = ws4 + (size_t)s * kStreamU4;
    const int t0 = tb * 248;

#pragma unroll
    for (int it = 0; it < 16; ++it) {
        const int r = it * 4 + wid;
        const float4 v = *(const float4*)(src + (size_t)(r0 + r) * kT + t0 + lane * 4);
        *(float4*)&tile[r * 260 + lane * 4] = v;   // b128, bank-spread (granule r*65+l)
    }
    __syncthreads();

    const int cbase = tb * 31;
#pragma unroll
    for (int it = 0; it < 8; ++it) {
        const int cl = it * 4 + wid;               // 0..31
        const int c8 = cbase + cl;                 // global chunk
        if (s == 4 && c8 >= kFiltC8) continue;     // obs only needed t<336
        const float* rp = &tile[lane * 260 + cl * 8];
        const float4 f0 = *(const float4*)(rp);
        const float4 f1 = *(const float4*)(rp + 4);
        union { __half2 h; unsigned u; } c0, c1, c2, c3;
        c0.h = __floats2half2_rn(f0.x, f0.y);
        c1.h = __floats2half2_rn(f0.z, f0.w);
        c2.h = __floats2half2_rn(f1.x, f1.y);
        c3.h = __floats2half2_rn(f1.z, f1.w);
        uint4 u; u.x = c0.u; u.y = c1.u; u.z = c2.u; u.w = c3.u;
        dst[(size_t)c8 * kB + r0 + lane] = u;      // 1KB/wave contiguous
    }
}

// ---------------------------------------------------------------------------
// Pass 2: the scan. 256 blocks x 64 threads; lane <-> row b0+lane.
// ---------------------------------------------------------------------------
__device__ inline void up2(unsigned u, float& a, float& b) {
    union { unsigned u; __half2 h; } cv; cv.u = u;
    const float2 f = __half22float2(cv.h);
    a = f.x; b = f.y;
}
__device__ inline void up8(uint4 u, float* v) {
    up2(u.x, v[0], v[1]); up2(u.y, v[2], v[3]);
    up2(u.z, v[4], v[5]); up2(u.w, v[6], v[7]);
}

struct Qc { uint4 a, w, p, d, y; };

__global__ __launch_bounds__(64, 1)
void kf_scan_x(const uint4* __restrict__ X,
               const float* __restrict__ s_k_raw,
               const float* __restrict__ s_log_q,
               const float* __restrict__ s_log_r,
               const float* __restrict__ s_log_p0,
               const float* __restrict__ s_log_qs,
               const float* __restrict__ s_th_pl,
               const float* __restrict__ s_th_pq,
               const float* __restrict__ s_th_wc,
               const float* __restrict__ s_th_s,
               const float* __restrict__ s_th_fc,
               float* __restrict__ out)
{
    extern __shared__ float lt[];        // [64][172] T-out, then [64][172] V-out
    float* ldsT = lt;
    float* ldsV = lt + 64 * 172;
    const int lane = threadIdx.x;
    const int b0 = blockIdx.x * 64;

    const uint4* XA = X;
    const uint4* XW = X + kStreamU4;
    const uint4* XP = X + 2 * kStreamU4;
    const uint4* XD = X + 3 * kStreamU4;
    const uint4* XY = X + 4 * kStreamU4;

    const float kpar = log1pf(expf(s_k_raw[0]));
    const float qq   = expf(s_log_q[0]) * expf(s_log_qs[0]);
    const float R    = expf(s_log_r[0]);
    float P          = expf(s_log_p0[0]);
    const float th_pl = s_th_pl[0], th_pq = s_th_pq[0], th_wc = s_th_wc[0];
    const float th_s  = s_th_s[0],  th_fc = s_th_fc[0];

    float Tst = 0.0f, aC = 0.0f, wC = 0.0f, pC = 0.0f;

    auto load = [&](Qc& q, int c) {
        const int nc = c < kC8 ? c : kC8 - 1;
        const size_t off = (size_t)nc * kB + b0 + lane;
        q.a = XA[off]; q.w = XW[off]; q.p = XP[off]; q.d = XD[off];
        const int yc = nc < kFiltC8 ? nc : kFiltC8 - 1;
        q.y = XY[(size_t)yc * kB + b0 + lane];
        __builtin_amdgcn_sched_barrier(0);   // pin: keep pipeline issued early
    };

    auto kstep = [&](float Ta, float w, float p, float draw, float y) {
        const float dtt = fmaxf(draw, 1.0f);
        const float dT = Tst - Ta;
        const float gk = fmaf(th_fc, w, th_s) - kpar;
        const float base = fmaf(p, fmaf(th_pq, p, th_pl), th_wc * w);
        const float Tp = fminf(fmaxf(fmaf(fmaf(gk, dT, base), dtt, Tst), -50.0f), 100.0f);
        const float F = fminf(fmaxf(fmaf(gk, dtt, 1.0f), -2.0f), 2.0f);
        const float Pp = fminf(fmaxf(fmaf(F * F, P, qq * dtt), 1e-10f), 1e6f);
        const float Kg = Pp * __builtin_amdgcn_rcpf(Pp + R);
        Tst = fmaf(Kg, y - Tp, Tp);
        const float omk = 1.0f - Kg;
        P = fmaf(omk * omk, Pp, Kg * Kg * R);
    };
    auto fstep = [&](float Ta, float w, float p, float draw) {
        const float dtt = fmaxf(draw, 1.0f);
        const float dT = Tst - Ta;
        const float gk = fmaf(th_fc, w, th_s) - kpar;
        const float base = fmaf(p, fmaf(th_pq, p, th_pl), th_wc * w);
        Tst = fminf(fmaxf(fmaf(fmaf(gk, dT, base), dtt, Tst), -50.0f), 100.0f);
        const float F = fminf(fmaxf(fmaf(gk, dtt, 1.0f), -2.0f), 2.0f);
        P = fminf(fmaxf(fmaf(F * F, P, qq * dtt), 1e-10f), 1e6f);
    };

    auto cK = [&](const Qc& q) {
        float A[8], W[8], Pr[8], D[8], Y[8];
        up8(q.a, A); up8(q.w, W); up8(q.p, Pr); up8(q.d, D); up8(q.y, Y);
        kstep(aC, wC, pC, D[0], Y[0]);
#pragma unroll
        for (int j = 1; j < 8; ++j) kstep(A[j-1], W[j-1], Pr[j-1], D[j], Y[j]);
        aC = A[7]; wC = W[7]; pC = Pr[7];
    };

    auto cF = [&](const Qc& q, int c) {
        float A[8], W[8], Pr[8], D[8], oT[8], oV[8];
        up8(q.a, A); up8(q.w, W); up8(q.p, Pr); up8(q.d, D);
        fstep(aC, wC, pC, D[0]); oT[0] = Tst; oV[0] = P;
#pragma unroll
        for (int j = 1; j < 8; ++j) {
            fstep(A[j-1], W[j-1], Pr[j-1], D[j]);
            oT[j] = Tst; oV[j] = P;
        }
        aC = A[7]; wC = W[7]; pC = Pr[7];
        const int h0 = (c - kFiltC8) * 8;
        *(float4*)&ldsT[lane * 172 + h0    ] = make_float4(oT[0], oT[1], oT[2], oT[3]);
        *(float4*)&ldsT[lane * 172 + h0 + 4] = make_float4(oT[4], oT[5], oT[6], oT[7]);
        *(float4*)&ldsV[lane * 172 + h0    ] = make_float4(oV[0], oV[1], oV[2], oV[3]);
        *(float4*)&ldsV[lane * 172 + h0 + 4] = make_float4(oV[4], oV[5], oV[6], oV[7]);
    };

    // ---- prologue: depth-4 pipeline ----
    Qc q0, q1, q2, q3;
    load(q0, 0); load(q1, 1); load(q2, 2); load(q3, 3);

    // chunk 0 special: s0 = obs[0]; carries = A/W/P[0]; steps t=1..7
    {
        float A[8], W[8], Pr[8], D[8], Y[8];
        up8(q0.a, A); up8(q0.w, W); up8(q0.p, Pr); up8(q0.d, D); up8(q0.y, Y);
        Tst = Y[0];
        aC = A[0]; wC = W[0]; pC = Pr[0];
#pragma unroll
        for (int j = 1; j < 8; ++j) kstep(A[j-1], W[j-1], Pr[j-1], D[j], Y[j]);
        aC = A[7]; wC = W[7]; pC = Pr[7];
    }
    load(q0, 4);
    cK(q1); load(q1, 5);
    cK(q2); load(q2, 6);
    cK(q3); load(q3, 7);

    // filter chunks 4..39 (9 groups of 4)
#pragma unroll 1
    for (int g = 0; g < 9; ++g) {
        const int base = 4 * g + 4;
        cK(q0); load(q0, base + 4);
        cK(q1); load(q1, base + 5);
        cK(q2); load(q2, base + 6);
        cK(q3); load(q3, base + 7);
    }
    // chunks 40, 41 finish the filter (q0,q1); refills go to 44,45
    cK(q0); load(q0, 44);
    cK(q1); load(q1, 45);

    // forecast chunks 42..61 (5 groups of 4), rotation q2,q3,q0,q1
#pragma unroll 1
    for (int g = 0; g < 5; ++g) {
        const int base = kFiltC8 + 4 * g;
        cF(q2, base + 0); load(q2, base + 4);
        cF(q3, base + 1); load(q3, base + 5);
        cF(q0, base + 2); load(q0, base + 6);
        cF(q1, base + 3); load(q1, base + 7);
    }
    cF(q2, 62);  // last chunk

    // ---- epilogue: coalesced stores, 672 B per row (lanes 0..41) ----
    float* outT = out;
    float* outV = out + (size_t)kB * kH;
#pragma unroll 1
    for (int r = 0; r < 64; ++r) {
        if (lane < 42) {
            const float4 tv = *(const float4*)&ldsT[r * 172 + lane * 4];
            const float4 vv = *(const float4*)&ldsV[r * 172 + lane * 4];
            *(float4*)(outT + (size_t)(b0 + r) * kH + lane * 4) = tv;
            *(float4*)(outV + (size_t)(b0 + r) * kH + lane * 4) = vv;
        }
    }
}

// ---------------------------------------------------------------------------
// Fallback (R4 kernel, verbatim): used only if ws_size < kWsNeed.
// ---------------------------------------------------------------------------
namespace fb {
constexpr int kW = 16;
constexpr int kNW = 32;
constexpr int kFiltW = 21;
constexpr int kRS = 65;
constexpr int kTile = kW * kRS;
constexpr int kORS = 17;
constexpr int kOTile = 64 * kORS;
constexpr int oA  = 0;
constexpr int oWd = oA  + 2 * kTile;
constexpr int oP  = oWd + 2 * kTile;
constexpr int oD  = oP  + 2 * kTile;
constexpr int oY  = oD  + 2 * kTile;
constexpr int oOT = oY  + 2 * kTile;
constexpr int oOV = oOT + 2 * kOTile;
constexpr int kLdsWords = oOV + 2 * kOTile;
}

__global__ __launch_bounds__(256, 1)
void kf_kernel(const float* __restrict__ g_obs,
               const float* __restrict__ g_air,
               const float* __restrict__ g_wind,
               const float* __restrict__ g_par,
               const float* __restrict__ g_dt,
               const float* __restrict__ s_k_raw,
               const float* __restrict__ s_log_q,
               const float* __restrict__ s_log_r,
               const float* __restrict__ s_log_p0,
               const float* __restrict__ s_log_qs,
               const float* __restrict__ s_th_pl,
               const float* __restrict__ s_th_pq,
               const float* __restrict__ s_th_wc,
               const float* __restrict__ s_th_s,
               const float* __restrict__ s_th_fc,
               float* __restrict__ out)
{
    using namespace fb;
    __shared__ float lds[kLdsWords];
    const int tid  = threadIdx.x;
    const int wid  = tid >> 6;
    const int lane = tid & 63;
    const int r0   = blockIdx.x * 64;

    auto stage = [&](const float* __restrict__ g, int basew, int buf, int wn) {
        const int t0 = wn * kW;
        const int tb = basew + buf * kTile;
#pragma unroll
        for (int kk = 0; kk < 4; ++kk) {
            const int flat = kk * 64 + lane;
            const int row = flat >> 2, q = flat & 3;
            int tq = t0 + q * 4;
            tq = tq > 500 ? 500 : tq;
            const float4 v = *(const float4*)(g + (size_t)(r0 + row) * kT + tq);
            const int wb = tb + row + (q * 4) * kRS;
            lds[wb          ] = v.x;
            lds[wb +     kRS] = v.y;
            lds[wb + 2 * kRS] = v.z;
            lds[wb + 3 * kRS] = v.w;
        }
    };

    float* outT = out;
    float* outV = out + (size_t)kB * kH;

    auto store_out = [&](int wn) {
        const int buf = wn & 1;
        const int h0 = wn * kW - kL;
#pragma unroll
        for (int kk = 0; kk < 4; ++kk) {
            const int flat = kk * 64 + lane;
            const int row = flat >> 2, q = flat & 3;
            const int h = h0 + q * 4;
            if (h + 3 < kH) {
                const int rb = oOT + buf * kOTile + row * kORS + q * 4;
                const int vb = oOV + buf * kOTile + row * kORS + q * 4;
                float4 tv, vv;
                tv.x = lds[rb]; tv.y = lds[rb + 1]; tv.z = lds[rb + 2]; tv.w = lds[rb + 3];
                vv.x = lds[vb]; vv.y = lds[vb + 1]; vv.z = lds[vb + 2]; vv.w = lds[vb + 3];
                *(float4*)(outT + (size_t)(r0 + row) * kH + h) = tv;
                *(float4*)(outV + (size_t)(r0 + row) * kH + h) = vv;
            }
        }
    };

    float kpar = 0, qq = 0, R = 0, P = 0, Tst = 0;
    float th_pl = 0, th_pq = 0, th_wc = 0, th_s = 0, th_fc = 0;
    float aC = 0, wC = 0, pC = 0;

    if (wid == 0) {
        kpar = log1pf(expf(s_k_raw[0]));
        qq   = expf(s_log_q[0]) * expf(s_log_qs[0]);
        R    = expf(s_log_r[0]);
        P    = expf(s_log_p0[0]);
        th_pl = s_th_pl[0]; th_pq = s_th_pq[0]; th_wc = s_th_wc[0];
        th_s  = s_th_s[0];  th_fc = s_th_fc[0];
    } else if (wid == 1) {
        stage(g_air, oA, 0, 0); stage(g_wind, oWd, 0, 0);
    } else if (wid == 2) {
        stage(g_par, oP, 0, 0); stage(g_dt, oD, 0, 0);
    } else {
        stage(g_obs, oY, 0, 0);
    }
    __syncthreads();

    for (int w = 0; w < kNW; ++w) {
        const int buf = w & 1;
        if (wid == 0) {
            const int Ab = oA  + buf * kTile, Wb = oWd + buf * kTile;
            const int Pb = oP  + buf * kTile, Db = oD  + buf * kTile;
            const int Yb = oY  + buf * kTile;
            int trel = 0;
            if (w == 0) {
                Tst = lds[Yb + lane];
                aC = lds[Ab + lane]; wC = lds[Wb + lane]; pC = lds[Pb + lane];
                trel = 1;
            }
            if (w < kFiltW) {
                for (; trel < kW; ++trel) {
                    const float D = lds[Db + trel * kRS + lane];
                    const float Y = lds[Yb + trel * kRS + lane];
                    const float dtt = fmaxf(D, 1.0f);
                    const float dT = Tst - aC;
                    const float gk = fmaf(th_fc, wC, th_s) - kpar;
                    const float base = fmaf(pC, fmaf(th_pq, pC, th_pl), th_wc * wC);
                    const float Tp = fminf(fmaxf(fmaf(fmaf(gk, dT, base), dtt, Tst), -50.0f), 100.0f);
                    const float F = fminf(fmaxf(fmaf(gk, dtt, 1.0f), -2.0f), 2.0f);
                    const float Pp = fminf(fmaxf(fmaf(F * F, P, qq * dtt), 1e-10f), 1e6f);
                    const float Kg = Pp * __builtin_amdgcn_rcpf(Pp + R);
                    Tst = fmaf(Kg, Y - Tp, Tp);
                    const float omk = 1.0f - Kg;
                    P = fmaf(omk * omk, Pp, Kg * Kg * R);
                    aC = lds[Ab + trel * kRS + lane];
                    wC = lds[Wb + trel * kRS + lane];
                    pC = lds[Pb + trel * kRS + lane];
                }
            } else {
                const int tmax = (w == kNW - 1) ? 8 : kW;
                const int ob = oOT + buf * kOTile + lane * kORS;
                const int vb = oOV + buf * kOTile + lane * kORS;
                for (; trel < tmax; ++trel) {
                    const float D = lds[Db + trel * kRS + lane];
                    const float dtt = fmaxf(D, 1.0f);
                    const float dT = Tst - aC;
                    const float gk = fmaf(th_fc, wC, th_s) - kpar;
                    const float base = fmaf(pC, fmaf(th_pq, pC, th_pl), th_wc * wC);
                    Tst = fminf(fmaxf(fmaf(fmaf(gk, dT, base), dtt, Tst), -50.0f), 100.0f);
                    const float F = fminf(fmaxf(fmaf(gk, dtt, 1.0f), -2.0f), 2.0f);
                    P = fminf(fmaxf(fmaf(F * F, P, qq * dtt), 1e-10f), 1e6f);
                    lds[ob + trel] = Tst;
                    lds[vb + trel] = P;
                    aC = lds[Ab + trel * kRS + lane];
                    wC = lds[Wb + trel * kRS + lane];
                    pC = lds[Pb + trel * kRS + lane];
                }
            }
        } else if (wid == 1) {
            if (w + 1 < kNW) { stage(g_air, oA, (w + 1) & 1, w + 1);
                               stage(g_wind, oWd, (w + 1) & 1, w + 1); }
        } else if (wid == 2) {
            if (w + 1 < kNW) { stage(g_par, oP, (w + 1) & 1, w + 1);
                               stage(g_dt, oD, (w + 1) & 1, w + 1); }
        } else {
            if (w + 1 < kFiltW) stage(g_obs, oY, (w + 1) & 1, w + 1);
            if (w - 1 >= kFiltW) store_out(w - 1);
        }
        __syncthreads();
    }
    if (wid == 3) store_out(kNW - 1);
}

extern "C" void kernel_launch(void* const* d_in, const int* in_sizes, int n_in,
                              void* d_out, int out_size, void* d_ws, size_t ws_size,
                              hipStream_t stream) {
    const float* g_obs  = (const float*)d_in[0];
    const float* g_air  = (const float*)d_in[1];
    const float* g_wind = (const float*)d_in[2];
    const float* g_par  = (const float*)d_in[3];
    const float* g_dt   = (const float*)d_in[4];
    const float* k_raw  = (const float*)d_in[6];
    const float* log_q  = (const float*)d_in[7];
    const float* log_r  = (const float*)d_in[8];
    const float* log_p0 = (const float*)d_in[9];
    const float* log_qs = (const float*)d_in[10];
    const float* th_pl  = (const float*)d_in[11];
    const float* th_pq  = (const float*)d_in[12];
    const float* th_wc  = (const float*)d_in[13];
    const float* th_s   = (const float*)d_in[14];
    const float* th_fc  = (const float*)d_in[15];
    float* out = (float*)d_out;

    if (ws_size >= kWsNeed) {
        uint4* ws4 = (uint4*)d_ws;
        dim3 xg(kB / 64, 2, 5), xb(256);
        hipLaunchKernelGGL(xpose_kernel, xg, xb, 64 * 260 * 4, stream,
                           g_obs, g_air, g_wind, g_par, g_dt, ws4);
        dim3 sg(kB / 64), sb(64);
        hipLaunchKernelGGL(kf_scan_x, sg, sb, 2 * 64 * 172 * 4, stream,
                           (const uint4*)ws4,
                           k_raw, log_q, log_r, log_p0, log_qs,
                           th_pl, th_pq, th_wc, th_s, th_fc, out);
    } else {
        dim3 grid(kB / 64), block(256);
        hipLaunchKernelGGL(kf_kernel, grid, block, 0, stream,
                           g_obs, g_air, g_wind, g_par, g_dt,
                           k_raw, log_q, log_r, log_p0, log_qs,
                           th_pl, th_pq, th_wc, th_s, th_fc, out);
    }
}

// Round 6
// 220.532 us; speedup vs baseline: 1.1178x; 1.1178x over previous
//
#include <hip/hip_runtime.h>
#include <hip/hip_fp16.h>

// Fixed problem instance: B=16384, L=336, H=168, T=504.
// One-pass producer/consumer kernel. 256 blocks x 256 threads (4 waves),
// block owns 64 rows, 1 block/CU. No __syncthreads in steady state:
// wave0 = sequential KF scan (lane <-> row), reads fp16 tiles from LDS.
// wave1 = stage air+wind, wave2 = stage par+dt (coalesced b32 loads,
// transposed fp16 LDS writes), wave3 = stage obs (filter phase) then
// store output tiles (forecast phase). Double-buffered 16-step windows,
// synced by monotonic LDS counters (acquire/release, workgroup scope).
namespace {
constexpr int kB = 16384;
constexpr int kL = 336;
constexpr int kH = 168;
constexpr int kT = 504;
constexpr int kW = 16;            // window length (timesteps)
constexpr int kNW = 32;           // 32 windows x 16 = 512 >= 504
constexpr int kFW = 21;           // windows 0..20 filter (21*16 == 336), 21..31 forecast
constexpr int kIS = 66;           // input tile stride in halfs: [16 t][66]
constexpr int kITile = kW * kIS;  // 1056 halfs per stream-buffer
constexpr int kOS = 17;           // out tile stride floats: [64 rows][17]
constexpr int kOTile = 64 * kOS;  // 1088 floats
}

__device__ inline void fwait(int* f, int target) {
    int guard = 0;
    while (__hip_atomic_load(f, __ATOMIC_ACQUIRE, __HIP_MEMORY_SCOPE_WORKGROUP) < target) {
        __builtin_amdgcn_s_sleep(1);
        if (++guard > (1 << 22)) break;   // bailout: never hang the harness
    }
}
__device__ inline void fpost(int* f, int lane) {
    __threadfence_block();                // LDS writes visible before count bump
    if (lane == 0) atomicAdd(f, 1);
}

__global__ __launch_bounds__(256, 1)
void kf_fused(const float* __restrict__ g_obs,
              const float* __restrict__ g_air,
              const float* __restrict__ g_wind,
              const float* __restrict__ g_par,
              const float* __restrict__ g_dt,
              const float* __restrict__ s_k_raw,
              const float* __restrict__ s_log_q,
              const float* __restrict__ s_log_r,
              const float* __restrict__ s_log_p0,
              const float* __restrict__ s_log_qs,
              const float* __restrict__ s_th_pl,
              const float* __restrict__ s_th_pq,
              const float* __restrict__ s_th_wc,
              const float* __restrict__ s_th_s,
              const float* __restrict__ s_th_fc,
              float* __restrict__ out)
{
    __shared__ __half s_in[5][2][kITile];   // A,W,P,D,Y windows (fp16, [trel][row])
    __shared__ float  s_oT[2][kOTile];      // forecast T out-tiles [row][17]
    __shared__ float  s_oV[2][kOTile];      // forecast V out-tiles
    __shared__ int    s_flag[8];            // 0=pcAW 1=pcPD 2=pcY 3=cc 4=sc

    const int tid = threadIdx.x, wid = tid >> 6, lane = tid & 63;
    const int b0 = blockIdx.x * 64;

    if (tid < 8) s_flag[tid] = 0;
    __syncthreads();                        // the only barrier (flag init)

    int* pcAW = &s_flag[0];
    int* pcPD = &s_flag[1];
    int* pcY  = &s_flag[2];
    int* cc   = &s_flag[3];
    int* sc   = &s_flag[4];

    if (wid == 1 || wid == 2) {
        // ---- producers: 2 streams each, window w into buffer w&1 ----
        const float* g0 = (wid == 1) ? g_air  : g_par;
        const float* g1 = (wid == 1) ? g_wind : g_dt;
        __half* base0 = (wid == 1) ? &s_in[0][0][0] : &s_in[2][0][0];
        __half* base1 = (wid == 1) ? &s_in[1][0][0] : &s_in[3][0][0];
        int* pc = (wid == 1) ? pcAW : pcPD;
        const int rloc = lane >> 4, trel = lane & 15;
        for (int w = 0; w < kNW; ++w) {
            if (w >= 2) fwait(cc, w - 1);   // buffer free after consumer did w-2
            const int bi = w & 1;
            int t = w * kW + trel; if (t > kT - 1) t = kT - 1;  // window 31 clamp
            float v0[16], v1[16];
#pragma unroll
            for (int i = 0; i < 16; ++i) {  // 32 coalesced 256B loads in flight
                const size_t off = (size_t)(b0 + 4 * i + rloc) * kT + t;
                v0[i] = g0[off];
                v1[i] = g1[off];
            }
            __half* d0 = base0 + bi * kITile;
            __half* d1 = base1 + bi * kITile;
#pragma unroll
            for (int i = 0; i < 16; ++i) {
                const int idx = trel * kIS + 4 * i + rloc;
                d0[idx] = __float2half(v0[i]);
                d1[idx] = __float2half(v1[i]);
            }
            fpost(pc, lane);
        }
    } else if (wid == 3) {
        // ---- obs stager (filter windows), then output storer (forecast) ----
        const int rloc = lane >> 4, trel = lane & 15;
        for (int w = 0; w < kFW; ++w) {
            if (w >= 2) fwait(cc, w - 1);
            const int bi = w & 1;
            const int t = w * kW + trel;    // <= 335, no clamp needed
            float v[16];
#pragma unroll
            for (int i = 0; i < 16; ++i)
                v[i] = g_obs[(size_t)(b0 + 4 * i + rloc) * kT + t];
            __half* d = &s_in[4][bi][0];
#pragma unroll
            for (int i = 0; i < 16; ++i)
                d[trel * kIS + 4 * i + rloc] = __float2half(v[i]);
            fpost(pcY, lane);
        }
        const int rq = lane & 3, rr = lane >> 2;   // 16 rows x 4 quads per iter
        float* outT = out;
        float* outV = out + (size_t)kB * kH;
        for (int w = kFW; w < kNW; ++w) {
            fwait(cc, w + 1);               // consumer finished window w
            const int bi = w & 1;
            const int h0 = (w - kFW) * kW;
            const int nq = (w == kNW - 1) ? 2 : 4;  // window 31: 8 valid steps
#pragma unroll
            for (int i = 0; i < 4; ++i) {
                const int r = 16 * i + rr;
                if (rq < nq) {
                    const float4 tv = *(const float4*)&s_oT[bi][r * kOS + rq * 4];
                    const float4 vv = *(const float4*)&s_oV[bi][r * kOS + rq * 4];
                    *(float4*)&outT[(size_t)(b0 + r) * kH + h0 + rq * 4] = tv;
                    *(float4*)&outV[(size_t)(b0 + r) * kH + h0 + rq * 4] = vv;
                }
            }
            fpost(sc, lane);
        }
    } else {
        // ---- consumer: the sequential scan, lane <-> row ----
        const float kpar = log1pf(expf(s_k_raw[0]));
        const float qq   = expf(s_log_q[0]) * expf(s_log_qs[0]);
        const float R    = expf(s_log_r[0]);
        float P          = expf(s_log_p0[0]);
        const float th_pl = s_th_pl[0], th_pq = s_th_pq[0], th_wc = s_th_wc[0];
        const float th_s  = s_th_s[0],  th_fc = s_th_fc[0];
        float Tst = 0.0f, aC = 0.0f, wC = 0.0f, pC = 0.0f;

        for (int w = 0; w < kNW; ++w) {
            const int bi = w & 1;
            fwait(pcAW, w + 1);
            fwait(pcPD, w + 1);
            if (w < kFW) fwait(pcY, w + 1);
            if (w >= kFW + 2) fwait(sc, w - (kFW + 1));  // out-tile bi free

            const __half* A  = &s_in[0][bi][0];
            const __half* Wd = &s_in[1][bi][0];
            const __half* Pr = &s_in[2][bi][0];
            const __half* Dd = &s_in[3][bi][0];
            const __half* Yy = &s_in[4][bi][0];

            if (w < kFW) {
                int trel = 0;
                if (w == 0) {   // s0 = obs[0]; carries = A/W/P[0]
                    Tst = __half2float(Yy[lane]);
                    aC  = __half2float(A[lane]);
                    wC  = __half2float(Wd[lane]);
                    pC  = __half2float(Pr[lane]);
                    trel = 1;
                }
                for (; trel < kW; ++trel) {
                    const int ix = trel * kIS + lane;
                    const float dtt = fmaxf(__half2float(Dd[ix]), 1.0f);
                    const float y   = __half2float(Yy[ix]);
                    const float a   = __half2float(A[ix]);
                    const float wv  = __half2float(Wd[ix]);
                    const float pv  = __half2float(Pr[ix]);
                    const float dT  = Tst - aC;
                    const float gk  = fmaf(th_fc, wC, th_s) - kpar;
                    const float base = fmaf(pC, fmaf(th_pq, pC, th_pl), th_wc * wC);
                    const float Tp = fminf(fmaxf(fmaf(fmaf(gk, dT, base), dtt, Tst), -50.0f), 100.0f);
                    const float F  = fminf(fmaxf(fmaf(gk, dtt, 1.0f), -2.0f), 2.0f);
                    const float Pp = fminf(fmaxf(fmaf(F * F, P, qq * dtt), 1e-10f), 1e6f);
                    const float Kg = Pp * __builtin_amdgcn_rcpf(Pp + R);
                    Tst = fmaf(Kg, y - Tp, Tp);
                    const float omk = 1.0f - Kg;
                    P = fmaf(omk * omk, Pp, Kg * Kg * R);
                    aC = a; wC = wv; pC = pv;
                }
            } else {
                float* oT = &s_oT[bi][lane * kOS];
                float* oV = &s_oV[bi][lane * kOS];
#pragma unroll
                for (int trel = 0; trel < kW; ++trel) {  // steps past t=503 are
                    const int ix = trel * kIS + lane;    // clamped junk, not stored
                    const float dtt = fmaxf(__half2float(Dd[ix]), 1.0f);
                    const float a   = __half2float(A[ix]);
                    const float wv  = __half2float(Wd[ix]);
                    const float pv  = __half2float(Pr[ix]);
                    const float dT  = Tst - aC;
                    const float gk  = fmaf(th_fc, wC, th_s) - kpar;
                    const float base = fmaf(pC, fmaf(th_pq, pC, th_pl), th_wc * wC);
                    Tst = fminf(fmaxf(fmaf(fmaf(gk, dT, base), dtt, Tst), -50.0f), 100.0f);
                    const float F = fminf(fmaxf(fmaf(gk, dtt, 1.0f), -2.0f), 2.0f);
                    P = fminf(fmaxf(fmaf(F * F, P, qq * dtt), 1e-10f), 1e6f);
                    oT[trel] = Tst;
                    oV[trel] = P;
                    aC = a; wC = wv; pC = pv;
                }
            }
            fpost(cc, lane);
        }
    }
}

extern "C" void kernel_launch(void* const* d_in, const int* in_sizes, int n_in,
                              void* d_out, int out_size, void* d_ws, size_t ws_size,
                              hipStream_t stream) {
    const float* g_obs  = (const float*)d_in[0];
    const float* g_air  = (const float*)d_in[1];
    const float* g_wind = (const float*)d_in[2];
    const float* g_par  = (const float*)d_in[3];
    const float* g_dt   = (const float*)d_in[4];
    // d_in[5] = L_hist (int) -- compile-time constant for this instance
    const float* k_raw  = (const float*)d_in[6];
    const float* log_q  = (const float*)d_in[7];
    const float* log_r  = (const float*)d_in[8];
    const float* log_p0 = (const float*)d_in[9];
    const float* log_qs = (const float*)d_in[10];
    const float* th_pl  = (const float*)d_in[11];
    const float* th_pq  = (const float*)d_in[12];
    const float* th_wc  = (const float*)d_in[13];
    const float* th_s   = (const float*)d_in[14];
    const float* th_fc  = (const float*)d_in[15];
    float* out = (float*)d_out;

    dim3 grid(kB / 64), block(256);
    hipLaunchKernelGGL(kf_fused, grid, block, 0, stream,
                       g_obs, g_air, g_wind, g_par, g_dt,
                       k_raw, log_q, log_r, log_p0, log_qs,
                       th_pl, th_pq, th_wc, th_s, th_fc, out);
}

// Round 7
// 219.451 us; speedup vs baseline: 1.1233x; 1.0049x over previous
//
#include <hip/hip_runtime.h>

// Fixed problem instance: B=16384, L=336, H=168, T=504.
// One-pass producer/consumer. 256 blocks x 256 threads (4 waves), 64 rows/block,
// 1 block/CU. wave0 = sequential KF scan (lane<->row) from fp32 LDS tiles;
// wave1 stages air+wind, wave2 stages par+dt (float4 loads, 2 static register
// sets, issued 2 windows ahead); wave3 stages obs (filter) then stores outputs
// (forecast). Handshakes are LDS-only: s_waitcnt lgkmcnt(0) + relaxed LDS
// atomics -- NO vmcnt drain in the steady loop, so prefetch loads stay in
// flight across window boundaries.
namespace {
constexpr int kB = 16384;
constexpr int kL = 336;
constexpr int kH = 168;
constexpr int kT = 504;
constexpr int kW = 16;            // window length (timesteps)
constexpr int kNW = 32;           // 32 windows x 16 = 512 >= 504
constexpr int kFW = 21;           // windows 0..20 filter (21*16==336), 21..31 forecast
constexpr int kIS = 66;           // input tile stride (floats): [16 t][66]
constexpr int kITile = kW * kIS;  // 1056 floats per stream-buffer
constexpr int kOS = 17;           // out tile stride (floats): [64 rows][17]
constexpr int kOTile = 64 * kOS;  // 1088 floats
}

// Wait until *f >= target. Relaxed LDS poll + compiler barrier (all waves share
// this CU's LDS; producer completed its ds_writes before bumping the flag).
__device__ inline void fwait(int* f, int target) {
    int guard = 0;
    while (__hip_atomic_load(f, __ATOMIC_RELAXED, __HIP_MEMORY_SCOPE_WORKGROUP) < target) {
        __builtin_amdgcn_s_sleep(1);
        if (++guard > (1 << 22)) break;   // bailout: never hang the harness
    }
    asm volatile("" ::: "memory");        // no reads hoisted above the flag
}
// Publish: LDS ops drained (lgkm only -- vmcnt untouched!), then bump flag.
__device__ inline void fpost(int* f, int lane) {
    asm volatile("s_waitcnt lgkmcnt(0)" ::: "memory");
    if (lane == 0)
        __hip_atomic_fetch_add(f, 1, __ATOMIC_RELAXED, __HIP_MEMORY_SCOPE_WORKGROUP);
}

__global__ __launch_bounds__(256, 1)
void kf_fused(const float* __restrict__ g_obs,
              const float* __restrict__ g_air,
              const float* __restrict__ g_wind,
              const float* __restrict__ g_par,
              const float* __restrict__ g_dt,
              const float* __restrict__ s_k_raw,
              const float* __restrict__ s_log_q,
              const float* __restrict__ s_log_r,
              const float* __restrict__ s_log_p0,
              const float* __restrict__ s_log_qs,
              const float* __restrict__ s_th_pl,
              const float* __restrict__ s_th_pq,
              const float* __restrict__ s_th_wc,
              const float* __restrict__ s_th_s,
              const float* __restrict__ s_th_fc,
              float* __restrict__ out)
{
    __shared__ float s_in[5][2][kITile];   // A,W,P,D,Y fp32 windows [trel][row]
    __shared__ float s_oT[2][kOTile];      // forecast T out-tiles [row][17]
    __shared__ float s_oV[2][kOTile];      // forecast V out-tiles
    __shared__ int   s_flag[8];            // 0=pcAW 1=pcPD 2=pcY 3=cc 4=sc

    const int tid = threadIdx.x, wid = tid >> 6, lane = tid & 63;
    const int b0 = blockIdx.x * 64;

    if (tid < 8) s_flag[tid] = 0;
    __syncthreads();                       // the only barrier (flag init)

    int* pcAW = &s_flag[0];
    int* pcPD = &s_flag[1];
    int* pcY  = &s_flag[2];
    int* cc   = &s_flag[3];
    int* sc   = &s_flag[4];

    const int iq = lane & 3;               // t-quad within window (0..3)
    const int ir = lane >> 2;              // row within 16-row group

    // Issue the 4 float4 loads (1KB/instr) of stream g, window w, into r[4].
    auto issue = [&](const float* __restrict__ g, int w, float4* r) {
        int t = w * kW + iq * 4;
        if (t > kT - 4) t = kT - 4;        // window 31: quads 2,3 clamp to t=500
#pragma unroll
        for (int i = 0; i < 4; ++i)
            r[i] = *(const float4*)(g + (size_t)(b0 + 16 * i + ir) * kT + t);
    };
    // Transpose-stash r[4] into LDS tile [trel][row]. <=2-way bank aliasing.
    auto stash = [&](const float4* r, float* dst) {
        const int tb = iq * 4;
#pragma unroll
        for (int i = 0; i < 4; ++i) {
            const int row = 16 * i + ir;
            dst[(tb + 0) * kIS + row] = r[i].x;
            dst[(tb + 1) * kIS + row] = r[i].y;
            dst[(tb + 2) * kIS + row] = r[i].z;
            dst[(tb + 3) * kIS + row] = r[i].w;
        }
    };

    if (wid == 1 || wid == 2) {
        // ---- producers: 2 streams each, 2 static register sets, depth-2 ----
        const float* g0 = (wid == 1) ? g_air  : g_par;
        const float* g1 = (wid == 1) ? g_wind : g_dt;
        float* base0 = (wid == 1) ? &s_in[0][0][0] : &s_in[2][0][0];
        float* base1 = (wid == 1) ? &s_in[1][0][0] : &s_in[3][0][0];
        int* pc = (wid == 1) ? pcAW : pcPD;

        float4 a0[4], b0r[4], a1[4], b1r[4];
        issue(g0, 0, a0); issue(g1, 0, b0r);
        issue(g0, 1, a1); issue(g1, 1, b1r);
        __builtin_amdgcn_sched_barrier(0);
        for (int w = 0; w < kNW; ++w) {
            if (w >= 2) fwait(cc, w - 1);  // buffer w&1 free
            if (w & 1) {
                stash(a1, base0 + kITile); stash(b1r, base1 + kITile);
                fpost(pc, lane);
                if (w + 2 < kNW) { issue(g0, w + 2, a1); issue(g1, w + 2, b1r); }
            } else {
                stash(a0, base0); stash(b0r, base1);
                fpost(pc, lane);
                if (w + 2 < kNW) { issue(g0, w + 2, a0); issue(g1, w + 2, b0r); }
            }
            __builtin_amdgcn_sched_barrier(0);  // pin: no sinking past backedge
        }
    } else if (wid == 3) {
        // ---- obs stager (filter windows), then output storer (forecast) ----
        float4 y0[4], y1[4];
        issue(g_obs, 0, y0); issue(g_obs, 1, y1);
        __builtin_amdgcn_sched_barrier(0);
        for (int w = 0; w < kFW; ++w) {
            if (w >= 2) fwait(cc, w - 1);
            if (w & 1) {
                stash(y1, &s_in[4][1][0]);
                fpost(pcY, lane);
                if (w + 2 < kFW) issue(g_obs, w + 2, y1);
            } else {
                stash(y0, &s_in[4][0][0]);
                fpost(pcY, lane);
                if (w + 2 < kFW) issue(g_obs, w + 2, y0);
            }
            __builtin_amdgcn_sched_barrier(0);
        }
        const int rq = lane & 3, rr = lane >> 2;   // 16 rows x 4 quads per iter
        float* outT = out;
        float* outV = out + (size_t)kB * kH;
        for (int w = kFW; w < kNW; ++w) {
            fwait(cc, w + 1);              // consumer finished window w
            const int bi = w & 1;
            const int h0 = (w - kFW) * kW;
            const int nq = (w == kNW - 1) ? 2 : 4;  // window 31: 8 valid steps
#pragma unroll
            for (int i = 0; i < 4; ++i) {
                const int r = 16 * i + rr;
                if (rq < nq) {
                    const float4 tv = *(const float4*)&s_oT[bi][r * kOS + rq * 4];
                    const float4 vv = *(const float4*)&s_oV[bi][r * kOS + rq * 4];
                    *(float4*)&outT[(size_t)(b0 + r) * kH + h0 + rq * 4] = tv;
                    *(float4*)&outV[(size_t)(b0 + r) * kH + h0 + rq * 4] = vv;
                }
            }
            fpost(sc, lane);
        }
    } else {
        // ---- consumer: the sequential scan, lane <-> row ----
        const float kpar = log1pf(expf(s_k_raw[0]));
        const float qq   = expf(s_log_q[0]) * expf(s_log_qs[0]);
        const float R    = expf(s_log_r[0]);
        float P          = expf(s_log_p0[0]);
        const float th_pl = s_th_pl[0], th_pq = s_th_pq[0], th_wc = s_th_wc[0];
        const float th_s  = s_th_s[0],  th_fc = s_th_fc[0];
        float Tst = 0.0f, aC = 0.0f, wC = 0.0f, pC = 0.0f;

        for (int w = 0; w < kNW; ++w) {
            const int bi = w & 1;
            fwait(pcAW, w + 1);
            fwait(pcPD, w + 1);
            if (w < kFW) fwait(pcY, w + 1);
            if (w >= kFW + 2) fwait(sc, w - (kFW + 1));  // out-tile bi free

            const float* A  = &s_in[0][bi][0];
            const float* Wd = &s_in[1][bi][0];
            const float* Pr = &s_in[2][bi][0];
            const float* Dd = &s_in[3][bi][0];
            const float* Yy = &s_in[4][bi][0];

            if (w < kFW) {
                int trel = 0;
                if (w == 0) {   // s0 = obs[0]; carries = A/W/P[0]
                    Tst = Yy[lane]; aC = A[lane]; wC = Wd[lane]; pC = Pr[lane];
                    trel = 1;
                }
                for (; trel < kW; ++trel) {
                    const int ix = trel * kIS + lane;
                    const float dtt = fmaxf(Dd[ix], 1.0f);
                    const float y   = Yy[ix];
                    const float a = A[ix], wv = Wd[ix], pv = Pr[ix];
                    const float dT  = Tst - aC;
                    const float gk  = fmaf(th_fc, wC, th_s) - kpar;
                    const float base = fmaf(pC, fmaf(th_pq, pC, th_pl), th_wc * wC);
                    const float Tp = fminf(fmaxf(fmaf(fmaf(gk, dT, base), dtt, Tst), -50.0f), 100.0f);
                    const float F  = fminf(fmaxf(fmaf(gk, dtt, 1.0f), -2.0f), 2.0f);
                    const float Pp = fminf(fmaxf(fmaf(F * F, P, qq * dtt), 1e-10f), 1e6f);
                    const float Kg = Pp * __builtin_amdgcn_rcpf(Pp + R);
                    Tst = fmaf(Kg, y - Tp, Tp);
                    const float omk = 1.0f - Kg;
                    P = fmaf(omk * omk, Pp, Kg * Kg * R);
                    aC = a; wC = wv; pC = pv;
                }
            } else {
                float* oT = &s_oT[bi][lane * kOS];
                float* oV = &s_oV[bi][lane * kOS];
#pragma unroll
                for (int trel = 0; trel < kW; ++trel) {  // steps past t=503 are
                    const int ix = trel * kIS + lane;    // clamped junk, unstored
                    const float dtt = fmaxf(Dd[ix], 1.0f);
                    const float a = A[ix], wv = Wd[ix], pv = Pr[ix];
                    const float dT  = Tst - aC;
                    const float gk  = fmaf(th_fc, wC, th_s) - kpar;
                    const float base = fmaf(pC, fmaf(th_pq, pC, th_pl), th_wc * wC);
                    Tst = fminf(fmaxf(fmaf(fmaf(gk, dT, base), dtt, Tst), -50.0f), 100.0f);
                    const float F = fminf(fmaxf(fmaf(gk, dtt, 1.0f), -2.0f), 2.0f);
                    P = fminf(fmaxf(fmaf(F * F, P, qq * dtt), 1e-10f), 1e6f);
                    oT[trel] = Tst;
                    oV[trel] = P;
                    aC = a; wC = wv; pC = pv;
                }
            }
            fpost(cc, lane);
        }
    }
}

extern "C" void kernel_launch(void* const* d_in, const int* in_sizes, int n_in,
                              void* d_out, int out_size, void* d_ws, size_t ws_size,
                              hipStream_t stream) {
    const float* g_obs  = (const float*)d_in[0];
    const float* g_air  = (const float*)d_in[1];
    const float* g_wind = (const float*)d_in[2];
    const float* g_par  = (const float*)d_in[3];
    const float* g_dt   = (const float*)d_in[4];
    // d_in[5] = L_hist (int) -- compile-time constant for this instance
    const float* k_raw  = (const float*)d_in[6];
    const float* log_q  = (const float*)d_in[7];
    const float* log_r  = (const float*)d_in[8];
    const float* log_p0 = (const float*)d_in[9];
    const float* log_qs = (const float*)d_in[10];
    const float* th_pl  = (const float*)d_in[11];
    const float* th_pq  = (const float*)d_in[12];
    const float* th_wc  = (const float*)d_in[13];
    const float* th_s   = (const float*)d_in[14];
    const float* th_fc  = (const float*)d_in[15];
    float* out = (float*)d_out;

    dim3 grid(kB / 64), block(256);
    hipLaunchKernelGGL(kf_fused, grid, block, 0, stream,
                       g_obs, g_air, g_wind, g_par, g_dt,
                       k_raw, log_q, log_r, log_p0, log_qs,
                       th_pl, th_pq, th_wc, th_s, th_fc, out);
}